// Round 2
// baseline (491.676 us; speedup 1.0000x reference)
//
#include <hip/hip_runtime.h>

// LoRA forward, FUSED: out[8192][4096] = (x[8192][4096] @ A^T) @ B^T * 2.0, fp32.
// One block = 16 output rows; h[16][16] lives in LDS only.
//   Phase A: h = x_tile @ A^T via bf16 MFMA hi/lo split (err ~1e-5), K=4096
//            split 1024-per-wave across 4 waves, cross-wave LDS reduce.
//   Phase B: out_tile = h @ B^T * 2 in fp32 VALU (B is L2-resident, 256 KB).
//
// Round-1 lesson: __launch_bounds__(512,4) capped VGPR at 128 while the kernel
// held 64-reg load bursts AND a 64-reg breg[] -> scratch spills = +500 MB HBM
// writes, latency-bound at 336 us. Fix: 256-thread blocks, 2-ktile load bursts
// (32 VGPRs in flight), peak pressure ~90-110 regs -> no spill under the
// 128-reg cap of __launch_bounds__(256,4) (16 waves/CU).

#define IN_F  4096
#define OUT_F 4096
#define RANK  16

typedef __attribute__((ext_vector_type(8))) short short8;   // 8 bf16 (4 VGPRs)
typedef __attribute__((ext_vector_type(4))) float f32x4;

static __device__ __forceinline__ short f2bf(float f) {
    union { float f; unsigned u; } v; v.f = f;
    unsigned r = v.u + 0x7fff + ((v.u >> 16) & 1);          // RNE
    return (short)(r >> 16);
}
static __device__ __forceinline__ float bf2f(short h) {
    union { unsigned u; float f; } v; v.u = ((unsigned)(unsigned short)h) << 16;
    return v.f;
}

// block = 256 threads (4 waves), grid = 512 blocks (16 rows each; 4 blocks/CU
// capacity at 128 VGPR -> whole grid co-resident).
// frag layouts (16x16x32 bf16): A/B-frag idx=lane&15, k=(lane>>4)*8+j;
// D: col(n)=lane&15, row(m)=(lane>>4)*4+reg  -- verified in prior session.
__global__ __launch_bounds__(256, 4) void k_fused(const float* __restrict__ x,
                                                  const float* __restrict__ A,
                                                  const float* __restrict__ B,
                                                  float* __restrict__ out) {
    __shared__ float hpart[4][16][16];          // 4 KB: per-wave partial h
    __shared__ float hs[16 * RANK];             // 1 KB: reduced h * 2.0

    const int tid  = threadIdx.x;
    const int w    = __builtin_amdgcn_readfirstlane(tid >> 6);  // wave 0..3
    const int lane = tid & 63;
    const int n    = lane & 15;                 // x-row / A-rank within frag
    const int q    = lane >> 4;                 // k-quad
    const int row0 = blockIdx.x * 16;
    const int k0   = w * 1024;                  // this wave's K slice

    // ---------------- Phase A: partial h = x_tile @ A^T (MFMA) ----------------
    f32x4 acc = {0.f, 0.f, 0.f, 0.f};
    const float* xr = x + (size_t)(row0 + n) * IN_F + k0 + q * 8;
    const float* ar = A + (size_t)n * IN_F + k0 + q * 8;

    for (int g = 0; g < 16; ++g) {              // 16 groups x 2 ktiles(32) = 1024 k
        // burst of 8 float4 loads (32 VGPRs in flight) -- fits 128-reg budget
        float4 a0[2], a1[2], v0[2], v1[2];
#pragma unroll
        for (int kt = 0; kt < 2; ++kt) {
            const float* ap = ar + (size_t)(g * 2 + kt) * 32;
            const float* xp = xr + (size_t)(g * 2 + kt) * 32;
            a0[kt] = *(const float4*)ap;
            a1[kt] = *(const float4*)(ap + 4);
            v0[kt] = *(const float4*)xp;
            v1[kt] = *(const float4*)(xp + 4);
        }
#pragma unroll
        for (int kt = 0; kt < 2; ++kt) {
            const float av[8] = {a0[kt].x, a0[kt].y, a0[kt].z, a0[kt].w,
                                 a1[kt].x, a1[kt].y, a1[kt].z, a1[kt].w};
            const float xv[8] = {v0[kt].x, v0[kt].y, v0[kt].z, v0[kt].w,
                                 v1[kt].x, v1[kt].y, v1[kt].z, v1[kt].w};
            short8 Ahi, Alo, xhi, xlo;
#pragma unroll
            for (int j = 0; j < 8; ++j) {
                const short ah = f2bf(av[j]);
                Ahi[j] = ah;
                Alo[j] = f2bf(av[j] - bf2f(ah));
                const short xh = f2bf(xv[j]);
                xhi[j] = xh;
                xlo[j] = f2bf(xv[j] - bf2f(xh));
            }
            acc = __builtin_amdgcn_mfma_f32_16x16x32_bf16(xhi, Ahi, acc, 0, 0, 0);
            acc = __builtin_amdgcn_mfma_f32_16x16x32_bf16(xlo, Ahi, acc, 0, 0, 0);
            acc = __builtin_amdgcn_mfma_f32_16x16x32_bf16(xhi, Alo, acc, 0, 0, 0);
        }
    }

    // D layout: col(rank)=n, row=q*4+r
#pragma unroll
    for (int r = 0; r < 4; ++r)
        hpart[w][q * 4 + r][n] = acc[r];
    __syncthreads();

    // cross-wave reduce: thread t owns (row,rank)=(t>>4, t&15); fold SCALING=2
    {
        const float* hp = &hpart[0][0][0];
        float s = 0.f;
#pragma unroll
        for (int ww = 0; ww < 4; ++ww)
            s += hp[ww * 256 + tid];
        hs[tid] = 2.0f * s;
    }
    __syncthreads();

    // ---------------- Phase B: out_tile = h @ B^T (fp32 VALU) ----------------
    // 4 passes of 1024 cols; thread t covers cols {p*1024 + t*4 .. +3}.
    for (int p = 0; p < 4; ++p) {
        const int col = p * 1024 + tid * 4;
        // B slice into regs: bf[j*16 + rho] = B[col+j][rho]  (64 VGPRs, reused)
        float4 breg[16];
        const float4* B4 = (const float4*)(B + (size_t)col * RANK);
#pragma unroll
        for (int i = 0; i < 16; ++i) breg[i] = B4[i];
        const float* bf = (const float*)breg;

        for (int r = 0; r < 16; ++r) {
            const float4 h0 = *(const float4*)(hs + r * RANK);
            const float4 h1 = *(const float4*)(hs + r * RANK + 4);
            const float4 h2 = *(const float4*)(hs + r * RANK + 8);
            const float4 h3 = *(const float4*)(hs + r * RANK + 12);
            const float hv[16] = {h0.x, h0.y, h0.z, h0.w, h1.x, h1.y, h1.z, h1.w,
                                  h2.x, h2.y, h2.z, h2.w, h3.x, h3.y, h3.z, h3.w};
            float4 o = {0.f, 0.f, 0.f, 0.f};
#pragma unroll
            for (int rho = 0; rho < RANK; ++rho) {
                o.x += hv[rho] * bf[0 * RANK + rho];
                o.y += hv[rho] * bf[1 * RANK + rho];
                o.z += hv[rho] * bf[2 * RANK + rho];
                o.w += hv[rho] * bf[3 * RANK + rho];
            }
            *(float4*)(out + (size_t)(row0 + r) * OUT_F + col) = o;  // dwordx4
        }
    }
}

extern "C" void kernel_launch(void* const* d_in, const int* in_sizes, int n_in,
                              void* d_out, int out_size, void* d_ws, size_t ws_size,
                              hipStream_t stream) {
    const float* x  = (const float*)d_in[0];   // [4,2048,4096]
    const float* A  = (const float*)d_in[1];   // [16,4096]
    const float* Bm = (const float*)d_in[2];   // [4096,16]
    float* out = (float*)d_out;                // [8192,4096] fp32

    k_fused<<<512, 256, 0, stream>>>(x, A, Bm, out);
}

// Round 3
// 291.215 us; speedup vs baseline: 1.6884x; 1.6884x over previous
//
#include <hip/hip_runtime.h>

// LoRA forward, FUSED: out[8192][4096] = (x[8192][4096] @ A^T) @ B^T * 2.0, fp32.
// One block = 16 output rows; h[16][16] lives in LDS only.
//
// Round-1/2 lesson: pointer-cast local arrays (breg/bf, av/xv/hv) are allocas
// the compiler CANNOT promote (address taken) -> they live in SCRATCH = global
// memory. VGPR=64 + 430 MB excess FETCH + 250 MB excess WRITE = scratch
// round-trips, latency-bound at ~350 us. This version has ZERO local arrays:
// all state is named float4/short8 variables (constant-index vector subscripts
// are register ops).
//
// k_prep: A[16][4096] f32 -> bf16 hi/lo planes in ws (256 KB, L2-resident).
// k_fused Phase A: h = x_tile @ A^T via 3-term hi/lo bf16 MFMA (err ~1e-5),
//   K split 1024/wave across 4 waves, register ping-pong prefetch (8 loads in
//   flight), cross-wave LDS reduce.
// k_fused Phase B: out_tile = h @ B^T * 2 in fp32 VALU, B cached in 16 NAMED
//   float4 regs per 4-col slice.

#define IN_F  4096
#define OUT_F 4096
#define RANK  16

typedef __attribute__((ext_vector_type(8))) short short8;   // 8 bf16
typedef __attribute__((ext_vector_type(4))) short short4v;  // 4 bf16
typedef __attribute__((ext_vector_type(4))) float f32x4;

static __device__ __forceinline__ short f2bf(float f) {
    union { float f; unsigned u; } v; v.f = f;
    unsigned r = v.u + 0x7fff + ((v.u >> 16) & 1);          // RNE
    return (short)(r >> 16);
}
static __device__ __forceinline__ float bf2f(short h) {
    union { unsigned u; float f; } v; v.u = ((unsigned)(unsigned short)h) << 16;
    return v.f;
}
static __device__ __forceinline__ float dot4(float4 a, float4 b) {
    return fmaf(a.x, b.x, fmaf(a.y, b.y, fmaf(a.z, b.z, a.w * b.w)));
}

// ---------------- prep: A f32 -> Ahi/Alo bf16 planes ----------------
__global__ __launch_bounds__(256) void k_prep(const float* __restrict__ A,
                                              short* __restrict__ Ahi,
                                              short* __restrict__ Alo) {
    const int i = (blockIdx.x * 256 + threadIdx.x) * 4;     // 64 blocks -> 65536
    const float4 v = *(const float4*)(A + i);
    short4v hi, lo;
    { short h = f2bf(v.x); hi[0] = h; lo[0] = f2bf(v.x - bf2f(h)); }
    { short h = f2bf(v.y); hi[1] = h; lo[1] = f2bf(v.y - bf2f(h)); }
    { short h = f2bf(v.z); hi[2] = h; lo[2] = f2bf(v.z - bf2f(h)); }
    { short h = f2bf(v.w); hi[3] = h; lo[3] = f2bf(v.w - bf2f(h)); }
    *(short4v*)(Ahi + i) = hi;
    *(short4v*)(Alo + i) = lo;
}

// ---- macros over NAMED variables only (no arrays, no pointer-to-local) ----
#define LOADG(AH0, AL0, AH1, AL1, X0, X1, X2, X3, g)                      \
    AH0 = *(const short8*)(ah + (g) * 64);                                \
    AL0 = *(const short8*)(al + (g) * 64);                                \
    AH1 = *(const short8*)(ah + (g) * 64 + 32);                           \
    AL1 = *(const short8*)(al + (g) * 64 + 32);                           \
    X0  = *(const float4*)(xr + (g) * 64);                                \
    X1  = *(const float4*)(xr + (g) * 64 + 4);                            \
    X2  = *(const float4*)(xr + (g) * 64 + 32);                           \
    X3  = *(const float4*)(xr + (g) * 64 + 36);

#define CVT8(XH, XL, V0, V1) {                                            \
    short h_;                                                             \
    h_ = f2bf((V0).x); (XH)[0] = h_; (XL)[0] = f2bf((V0).x - bf2f(h_));   \
    h_ = f2bf((V0).y); (XH)[1] = h_; (XL)[1] = f2bf((V0).y - bf2f(h_));   \
    h_ = f2bf((V0).z); (XH)[2] = h_; (XL)[2] = f2bf((V0).z - bf2f(h_));   \
    h_ = f2bf((V0).w); (XH)[3] = h_; (XL)[3] = f2bf((V0).w - bf2f(h_));   \
    h_ = f2bf((V1).x); (XH)[4] = h_; (XL)[4] = f2bf((V1).x - bf2f(h_));   \
    h_ = f2bf((V1).y); (XH)[5] = h_; (XL)[5] = f2bf((V1).y - bf2f(h_));   \
    h_ = f2bf((V1).z); (XH)[6] = h_; (XL)[6] = f2bf((V1).z - bf2f(h_));   \
    h_ = f2bf((V1).w); (XH)[7] = h_; (XL)[7] = f2bf((V1).w - bf2f(h_)); }

#define CONSUME(AH0, AL0, AH1, AL1, X0, X1, X2, X3) {                     \
    short8 xh_, xl_;                                                      \
    CVT8(xh_, xl_, X0, X1)                                                \
    acc = __builtin_amdgcn_mfma_f32_16x16x32_bf16(xh_, AH0, acc, 0, 0, 0);\
    acc = __builtin_amdgcn_mfma_f32_16x16x32_bf16(xl_, AH0, acc, 0, 0, 0);\
    acc = __builtin_amdgcn_mfma_f32_16x16x32_bf16(xh_, AL0, acc, 0, 0, 0);\
    CVT8(xh_, xl_, X2, X3)                                                \
    acc = __builtin_amdgcn_mfma_f32_16x16x32_bf16(xh_, AH1, acc, 0, 0, 0);\
    acc = __builtin_amdgcn_mfma_f32_16x16x32_bf16(xl_, AH1, acc, 0, 0, 0);\
    acc = __builtin_amdgcn_mfma_f32_16x16x32_bf16(xh_, AL1, acc, 0, 0, 0); }

// block = 256 threads (4 waves), grid = 512 (2 blocks/CU -> allow 256 VGPR).
// frag layouts (16x16x32 bf16): A/B-frag idx=lane&15, k=(lane>>4)*8+j;
// D: col(n)=lane&15, row(m)=(lane>>4)*4+reg  -- verified in prior session.
__global__ __launch_bounds__(256, 2) void k_fused(const float* __restrict__ x,
                                                  const short* __restrict__ Ahi,
                                                  const short* __restrict__ Alo,
                                                  const float* __restrict__ B,
                                                  float* __restrict__ out) {
    __shared__ float hpart[4][16][16];          // 4 KB: per-wave partial h
    __shared__ __align__(16) float hs[16 * RANK];  // 1 KB: reduced h * 2.0

    const int tid  = threadIdx.x;
    const int w    = tid >> 6;                  // wave 0..3
    const int lane = tid & 63;
    const int n    = lane & 15;                 // x-row / A-rank within frag
    const int q    = lane >> 4;                 // k-quad
    const int row0 = blockIdx.x * 16;
    const int k0   = w * 1024;                  // this wave's K slice

    const float* xr = x   + (size_t)(row0 + n) * IN_F + k0 + q * 8;
    const short* ah = Ahi + n * IN_F + k0 + q * 8;
    const short* al = Alo + n * IN_F + k0 + q * 8;

    // ---------------- Phase A: partial h = x_tile @ A^T (MFMA) ----------------
    f32x4 acc = {0.f, 0.f, 0.f, 0.f};
    short8 cAh0, cAl0, cAh1, cAl1, nAh0, nAl0, nAh1, nAl1;
    float4 cx0, cx1, cx2, cx3, nx0, nx1, nx2, nx3;

    LOADG(cAh0, cAl0, cAh1, cAl1, cx0, cx1, cx2, cx3, 0)
#pragma unroll
    for (int g = 0; g < 16; ++g) {              // 16 groups x 64 k = 1024 k
        if (g < 15) { LOADG(nAh0, nAl0, nAh1, nAl1, nx0, nx1, nx2, nx3, g + 1) }
        CONSUME(cAh0, cAl0, cAh1, cAl1, cx0, cx1, cx2, cx3)
        if (g < 15) {                           // SSA-renamed away under unroll
            cAh0 = nAh0; cAl0 = nAl0; cAh1 = nAh1; cAl1 = nAl1;
            cx0 = nx0; cx1 = nx1; cx2 = nx2; cx3 = nx3;
        }
    }

    // D layout: col(rank)=n, row=q*4+r
    hpart[w][q * 4 + 0][n] = acc[0];
    hpart[w][q * 4 + 1][n] = acc[1];
    hpart[w][q * 4 + 2][n] = acc[2];
    hpart[w][q * 4 + 3][n] = acc[3];
    __syncthreads();

    // cross-wave reduce: thread t owns (row,rank)=(t>>4, t&15); fold SCALING=2
    {
        const float* hp = &hpart[0][0][0];
        float s = (hp[tid] + hp[256 + tid]) + (hp[512 + tid] + hp[768 + tid]);
        hs[tid] = 2.0f * s;
    }
    __syncthreads();

    // ---------------- Phase B: out_tile = h @ B^T (fp32 VALU) ----------------
    // 4 passes of 1024 cols; thread t covers cols {p*1024 + t*4 .. +3}.
    // B slice in 16 NAMED float4 regs (no array -> no scratch).
    for (int p = 0; p < 4; ++p) {
        const int col = p * 1024 + tid * 4;
        const float4* B4 = (const float4*)(B + (size_t)col * RANK);
        const float4 b00 = B4[0],  b01 = B4[1],  b02 = B4[2],  b03 = B4[3];
        const float4 b10 = B4[4],  b11 = B4[5],  b12 = B4[6],  b13 = B4[7];
        const float4 b20 = B4[8],  b21 = B4[9],  b22 = B4[10], b23 = B4[11];
        const float4 b30 = B4[12], b31 = B4[13], b32 = B4[14], b33 = B4[15];

        for (int r = 0; r < 16; ++r) {
            const float4 h0 = *(const float4*)(hs + r * RANK);
            const float4 h1 = *(const float4*)(hs + r * RANK + 4);
            const float4 h2 = *(const float4*)(hs + r * RANK + 8);
            const float4 h3 = *(const float4*)(hs + r * RANK + 12);
            float4 o;
            o.x = (dot4(h0, b00) + dot4(h1, b01)) + (dot4(h2, b02) + dot4(h3, b03));
            o.y = (dot4(h0, b10) + dot4(h1, b11)) + (dot4(h2, b12) + dot4(h3, b13));
            o.z = (dot4(h0, b20) + dot4(h1, b21)) + (dot4(h2, b22) + dot4(h3, b23));
            o.w = (dot4(h0, b30) + dot4(h1, b31)) + (dot4(h2, b32) + dot4(h3, b33));
            *(float4*)(out + (size_t)(row0 + r) * OUT_F + col) = o;  // dwordx4
        }
    }
}

extern "C" void kernel_launch(void* const* d_in, const int* in_sizes, int n_in,
                              void* d_out, int out_size, void* d_ws, size_t ws_size,
                              hipStream_t stream) {
    const float* x  = (const float*)d_in[0];   // [4,2048,4096]
    const float* A  = (const float*)d_in[1];   // [16,4096]
    const float* Bm = (const float*)d_in[2];   // [4096,16]
    float* out = (float*)d_out;                // [8192,4096] fp32

    short* Ahi = (short*)d_ws;                 // 128 KB
    short* Alo = Ahi + RANK * IN_F;            // 128 KB

    k_prep<<<64, 256, 0, stream>>>(d_in[1] ? (const float*)d_in[1] : 0, Ahi, Alo);
    k_fused<<<512, 256, 0, stream>>>(x, Ahi, Alo, Bm, out);
}